// Round 21
// baseline (235.739 us; speedup 1.0000x reference)
//
#include <hip/hip_runtime.h>
#include <hip/hip_bf16.h>

#define EMBED 1024
#define HEADS 16
#define HDIM 64
#define FFN 4096
#define SEQ 2048
#define BATCH 2
#define MTOT (BATCH*SEQ)
#define QSCALE 0.1803368801111137f   // 0.125 * log2(e)

typedef __attribute__((ext_vector_type(8))) short bf16x8;
typedef __attribute__((ext_vector_type(4))) float f32x4;
typedef __attribute__((ext_vector_type(16))) float f32x16;
typedef unsigned short u16;
typedef unsigned int u32;

__device__ __forceinline__ u16 f2bf(float f) {
  union { float f; unsigned u; } v; v.f = f;
  unsigned r = v.u + 0x7FFFu + ((v.u >> 16) & 1u);
  return (u16)(r >> 16);
}

__device__ __forceinline__ void async_ld16(const void* g, void* l) {
  __builtin_amdgcn_global_load_lds((const __attribute__((address_space(1))) void*)g,
                                   (__attribute__((address_space(3))) void*)l,
                                   16, 0, 0);
}

// QKV scatter into MFMA-fragment-major layouts (coalesced attention loads).
__device__ __forceinline__ void qkv_scatter(u16* qp, u16* kp, u16* vp,
                                            int row, int col, float v) {
  const int which = col >> 10, hh = (col >> 6) & 15, d = col & 63;
  const int bb = row >> 11, ss = row & 2047;
  const int bh = bb * 16 + hh;
  if (which == 0) {
    v *= QSCALE;
    size_t idx = ((((size_t)bh * 64 + (ss >> 5)) * 4 + (d >> 4)) << 9)
               + (((ss & 31) + 32 * ((d >> 3) & 1)) << 3) + (d & 7);
    qp[idx] = f2bf(v);
  } else if (which == 1) {
    size_t idx = ((((size_t)bh * 32 + (ss >> 6)) * 8 + (d >> 4) * 2 + ((ss >> 5) & 1)) << 9)
               + (((ss & 31) + 32 * ((d >> 3) & 1)) << 3) + (d & 7);
    kp[idx] = f2bf(v);
  } else {
    size_t idx = ((((size_t)bh * 32 + (ss >> 6)) * 8 + ((ss & 63) >> 4) * 2 + (d >> 5)) << 9)
               + (((d & 31) + 32 * ((ss >> 3) & 1)) << 3) + (ss & 7);
    vp[idx] = f2bf(v);
  }
}

// ---------------- fp32 -> bf16 convert (vectorized) ----------------
__global__ __launch_bounds__(256) void k_cvt(const float* __restrict__ in,
                                             u16* __restrict__ out, int n4) {
  int i = blockIdx.x * 256 + threadIdx.x;
  int st = gridDim.x * 256;
  for (; i < n4; i += st) {
    float4 v = ((const float4*)in)[i];
    ushort4 o;
    o.x = f2bf(v.x); o.y = f2bf(v.y); o.z = f2bf(v.z); o.w = f2bf(v.w);
    ((ushort4*)out)[i] = o;
  }
}

// ---------------- transpose-convert: w[K,N] fp32 -> wT[N,K] bf16 ----------------
__global__ __launch_bounds__(256) void k_tr(const float* __restrict__ w,
                                            u16* __restrict__ wT, int K, int N) {
  __shared__ u16 tile[32][33];
  int n0 = blockIdx.x * 32, k0 = blockIdx.y * 32;
  int tx = threadIdx.x, ty = threadIdx.y;   // blockDim (32,8)
  #pragma unroll
  for (int i = 0; i < 4; ++i) {
    int k = k0 + ty + i * 8;
    tile[ty + i * 8][tx] = f2bf(w[(size_t)k * N + n0 + tx]);
  }
  __syncthreads();
  #pragma unroll
  for (int i = 0; i < 4; ++i) {
    int n = n0 + ty + i * 8;
    wT[(size_t)n * K + k0 + tx] = tile[tx][ty + i * 8];
  }
}

// ======== 8-phase 256x256 GEMM: counted vmcnt, one barrier/phase, =========
// quadrant order (0,0)->(1,0)->(1,1)->(0,1) with register-cached shared
// fragments. Stage issue A0@P1,B0@P2,A1@P3,B1@P4; gates VM4,VM4,-,VM4.
template <int OMODE, bool RELU>
__global__ __launch_bounds__(512) void k_gemm8(
    const u16* __restrict__ A, const u16* __restrict__ BT,
    const float* __restrict__ bias,
    void* __restrict__ out0, void* __restrict__ out1, void* __restrict__ out2,
    int M, int N, int K, int ldk) {
  __shared__ __align__(16) u16 As[2][2][128 * 64];
  __shared__ __align__(16) u16 Bs[2][2][128 * 64];
  const int tid = threadIdx.x;
  const int lane = tid & 63, g = lane >> 4, li = lane & 15;
  const int wid = tid >> 6, wm = wid >> 2, wn = wid & 3;

  const int gx = gridDim.x;
  const int nwg = gx * gridDim.y;
  const int flat = blockIdx.y * gx + blockIdx.x;
  const int cpx = nwg >> 3;
  const int swz = (flat & 7) * cpx + (flat >> 3);
  const int m0 = (swz / gx) * 256, n0 = (swz % gx) * 256;
  const int kchunk = blockIdx.z * K;

  f32x4 acc[8][4] = {};

  const u16* Ablk = A + (size_t)m0 * ldk + kchunk;
  const u16* Bblk = BT + (size_t)n0 * ldk + kchunk;
  const int trow = tid >> 3;                    // 0..63
  const int sc = (tid & 7) ^ (trow & 7);        // swizzled source chunk

  auto stageA = [&](int buf, int h, int kt) {
    #pragma unroll
    for (int r = 0; r < 2; ++r)
      async_ld16(Ablk + (size_t)(h * 64 + r * 128 + trow) * ldk + kt + sc * 8,
                 &As[buf][h][0] + r * 4096 + tid * 8);
  };
  auto stageB = [&](int buf, int h, int kt) {
    #pragma unroll
    for (int r = 0; r < 2; ++r) {
      const int p = trow + r * 64;
      async_ld16(Bblk + (size_t)(((p >> 5) << 6) + h * 32 + (p & 31)) * ldk + kt + sc * 8,
                 &Bs[buf][h][0] + r * 4096 + tid * 8);
    }
  };

#define VM4_ asm volatile("s_waitcnt vmcnt(4)" ::: "memory")
#define VM2_ asm volatile("s_waitcnt vmcnt(2)" ::: "memory")
#define VM0_ asm volatile("s_waitcnt vmcnt(0)" ::: "memory")
#define VMN_
#define GP8(IH, JH, READA, READB, VMSTMT, STAGE_STMT) do {                     \
    if (READA) {                                                               \
      _Pragma("unroll")                                                        \
      for (int i2 = 0; i2 < 4; ++i2) {                                         \
        const int pa = wm * 64 + i2 * 16 + li;                                 \
        _Pragma("unroll")                                                      \
        for (int ks = 0; ks < 2; ++ks)                                         \
          a_[i2][ks] = *(const bf16x8*)(&As[cur][IH][0] + pa * 64 +            \
                                        (((ks * 4 + g) ^ (li & 7)) * 8));      \
      }                                                                        \
    }                                                                          \
    if (READB) {                                                               \
      _Pragma("unroll")                                                        \
      for (int j2 = 0; j2 < 2; ++j2) {                                         \
        const int pb = wn * 32 + j2 * 16 + li;                                 \
        _Pragma("unroll")                                                      \
        for (int ks = 0; ks < 2; ++ks)                                         \
          b_[j2][ks] = *(const bf16x8*)(&Bs[cur][JH][0] + pb * 64 +            \
                                        (((ks * 4 + g) ^ (li & 7)) * 8));      \
      }                                                                        \
    }                                                                          \
    STAGE_STMT;                                                                \
    VMSTMT;                                                                    \
    __builtin_amdgcn_s_barrier();                                              \
    asm volatile("s_waitcnt lgkmcnt(0)" ::: "memory");                         \
    __builtin_amdgcn_sched_barrier(0);                                         \
    __builtin_amdgcn_s_setprio(1);                                             \
    _Pragma("unroll")                                                          \
    for (int ks = 0; ks < 2; ++ks)                                             \
      _Pragma("unroll")                                                        \
      for (int i2 = 0; i2 < 4; ++i2)                                           \
        _Pragma("unroll")                                                      \
        for (int j2 = 0; j2 < 2; ++j2)                                         \
          acc[IH * 4 + i2][JH * 2 + j2] = __builtin_amdgcn_mfma_f32_16x16x32_bf16( \
              a_[i2][ks], b_[j2][ks], acc[IH * 4 + i2][JH * 2 + j2], 0, 0, 0); \
    __builtin_amdgcn_s_setprio(0);                                             \
    asm volatile("" ::: "memory");                                             \
  } while (0)

  stageA(0, 0, 0); stageB(0, 0, 0); stageA(0, 1, 0); stageB(0, 1, 0);
  VM4_;   // A0,B0 of tile 0 done
  __builtin_amdgcn_s_barrier();
  asm volatile("" ::: "memory");

  int cur = 0;
  const int nkt = K >> 6;
  bf16x8 a_[4][2], b_[2][2];
  for (int t = 0; t < nkt - 1; ++t) {
    const int kn = (t + 1) * 64;
    GP8(0, 0, 1, 1, VM4_, stageA(cur ^ 1, 0, kn));   // gate: A1(t) done
    GP8(1, 0, 1, 0, VM4_, stageB(cur ^ 1, 0, kn));   // gate: B1(t) done
    GP8(1, 1, 0, 1, VMN_, stageA(cur ^ 1, 1, kn));
    GP8(0, 1, 1, 0, VM4_, stageB(cur ^ 1, 1, kn));   // gate: A0,B0(t+1) done
    cur ^= 1;
  }
  GP8(0, 0, 1, 1, VM2_, );
  GP8(1, 0, 1, 0, VM0_, );
  GP8(1, 1, 0, 1, VMN_, );
  GP8(0, 1, 1, 0, VMN_, );
#undef GP8
#undef VM4_
#undef VM2_
#undef VM0_
#undef VMN_

  float bcol[4];
  #pragma unroll
  for (int j = 0; j < 4; ++j)
    bcol[j] = (OMODE == 3) ? 0.f : bias[n0 + wn * 64 + j * 16 + li];

  #pragma unroll
  for (int i = 0; i < 8; ++i) {
    #pragma unroll
    for (int j = 0; j < 4; ++j) {
      #pragma unroll
      for (int r = 0; r < 4; ++r) {
        int row = m0 + wm * 128 + i * 16 + g * 4 + r;
        int col = n0 + wn * 64 + j * 16 + li;
        float v = acc[i][j][r] + bcol[j];
        if (RELU) v = fmaxf(v, 0.f);
        if (OMODE == 0) {
          ((u16*)out0)[(size_t)row * N + col] = f2bf(v);
        } else if (OMODE == 3) {
          ((float*)out0)[(size_t)blockIdx.z * M * N + (size_t)row * N + col] = v;
        } else {
          qkv_scatter((u16*)out0, (u16*)out1, (u16*)out2, row, col, v);
        }
      }
    }
  }
}

// ===== k_gemmD: 128x128 GEMM for the N=1024 out-proj. 8 waves, BK=64, =====
// 2 phases/K-tile, 4 LDS buffers, stage 2 ahead, counted vmcnt gates,
// one barrier per phase.
template <bool RELU>
__global__ __launch_bounds__(512) void k_gemmD(
    const u16* __restrict__ A, const u16* __restrict__ BT,
    const float* __restrict__ bias, float* __restrict__ out,
    int M, int N, int K) {
  __shared__ __align__(16) u16 As[4][2][64 * 64];
  __shared__ __align__(16) u16 Bs[4][2][64 * 64];
  const int tid = threadIdx.x;
  const int lane = tid & 63, g = lane >> 4, li = lane & 15;
  const int wid = tid >> 6, wm = wid >> 2, wn = wid & 3;

  const int gx = gridDim.x;
  const int nwg = gx * gridDim.y;
  const int flat = blockIdx.y * gx + blockIdx.x;
  const int cpx = nwg >> 3;
  const int swz = (flat & 7) * cpx + (flat >> 3);
  const int m0 = (swz / gx) * 128, n0 = (swz % gx) * 128;

  f32x4 acc[4][2] = {};

  const u16* Ablk = A + (size_t)m0 * K;
  const u16* Bblk = BT + (size_t)n0 * K;
  const int p = tid >> 3;
  const int c = (tid & 7) ^ (p & 7);

  auto stageAll = [&](int buf, int kt) {
    {
      const int grow = (p >> 5) * 64 + 0 * 32 + (p & 31);
      async_ld16(Ablk + (size_t)grow * K + kt + c * 8, &As[buf][0][0] + tid * 8);
    }
    {
      const int grow = (p >> 4) * 32 + 0 * 16 + (p & 15);
      async_ld16(Bblk + (size_t)grow * K + kt + c * 8, &Bs[buf][0][0] + tid * 8);
    }
    {
      const int grow = (p >> 4) * 32 + 1 * 16 + (p & 15);
      async_ld16(Bblk + (size_t)grow * K + kt + c * 8, &Bs[buf][1][0] + tid * 8);
    }
    {
      const int grow = (p >> 5) * 64 + 1 * 32 + (p & 31);
      async_ld16(Ablk + (size_t)grow * K + kt + c * 8, &As[buf][1][0] + tid * 8);
    }
  };

#define GATE(n) asm volatile("s_waitcnt vmcnt(" #n ")" ::: "memory")
  stageAll(0, 0);
  stageAll(1, 64);
  GATE(5);
  __builtin_amdgcn_s_barrier();
  asm volatile("" ::: "memory");

  const int nkt = K >> 6;
  const int pa0 = wm * 32 + li, pa1 = wm * 32 + 16 + li;
  const int pb = wn * 16 + li;
  for (int t = 0; t < nkt; ++t) {
    const int buf = t & 3;
    bf16x8 a_[2][2], b_[2][2];
    #pragma unroll
    for (int ks = 0; ks < 2; ++ks) {
      a_[0][ks] = *(const bf16x8*)(&As[buf][0][0] + pa0 * 64 + (((ks * 4 + g) ^ (pa0 & 7)) * 8));
      a_[1][ks] = *(const bf16x8*)(&As[buf][0][0] + pa1 * 64 + (((ks * 4 + g) ^ (pa1 & 7)) * 8));
      b_[0][ks] = *(const bf16x8*)(&Bs[buf][0][0] + pb * 64 + (((ks * 4 + g) ^ (pb & 7)) * 8));
      b_[1][ks] = *(const bf16x8*)(&Bs[buf][1][0] + pb * 64 + (((ks * 4 + g) ^ (pb & 7)) * 8));
    }
    if (t + 2 < nkt) {
      stageAll((t + 2) & 3, (t + 2) * 64);
      GATE(8);
    } else if (t + 1 < nkt) {
      GATE(4);
    } else {
      GATE(0);
    }
    __builtin_amdgcn_s_barrier();
    asm volatile("s_waitcnt lgkmcnt(0)" ::: "memory");
    __builtin_amdgcn_sched_barrier(0);
    __builtin_amdgcn_s_setprio(1);
    #pragma unroll
    for (int ks = 0; ks < 2; ++ks)
      #pragma unroll
      for (int i2l = 0; i2l < 2; ++i2l)
        #pragma unroll
        for (int j2 = 0; j2 < 2; ++j2)
          acc[i2l][j2] = __builtin_amdgcn_mfma_f32_16x16x32_bf16(
              a_[i2l][ks], b_[j2][ks], acc[i2l][j2], 0, 0, 0);
    __builtin_amdgcn_s_setprio(0);
    asm volatile("" ::: "memory");
    #pragma unroll
    for (int ks = 0; ks < 2; ++ks) {
      a_[0][ks] = *(const bf16x8*)(&As[buf][1][0] + pa0 * 64 + (((ks * 4 + g) ^ (pa0 & 7)) * 8));
      a_[1][ks] = *(const bf16x8*)(&As[buf][1][0] + pa1 * 64 + (((ks * 4 + g) ^ (pa1 & 7)) * 8));
    }
    if (t + 2 < nkt)      GATE(5);
    else if (t + 1 < nkt) GATE(1);
    __builtin_amdgcn_s_barrier();
    asm volatile("s_waitcnt lgkmcnt(0)" ::: "memory");
    __builtin_amdgcn_sched_barrier(0);
    __builtin_amdgcn_s_setprio(1);
    #pragma unroll
    for (int ks = 0; ks < 2; ++ks)
      #pragma unroll
      for (int i2l = 0; i2l < 2; ++i2l)
        #pragma unroll
        for (int j2 = 0; j2 < 2; ++j2)
          acc[2 + i2l][j2] = __builtin_amdgcn_mfma_f32_16x16x32_bf16(
              a_[i2l][ks], b_[j2][ks], acc[2 + i2l][j2], 0, 0, 0);
    __builtin_amdgcn_s_setprio(0);
    asm volatile("" ::: "memory");
  }
#undef GATE

  float bcol[2];
  #pragma unroll
  for (int j = 0; j < 2; ++j) bcol[j] = bias[n0 + wn * 32 + j * 16 + li];

  #pragma unroll
  for (int i = 0; i < 4; ++i) {
    #pragma unroll
    for (int j = 0; j < 2; ++j) {
      #pragma unroll
      for (int r = 0; r < 4; ++r) {
        int row = m0 + wm * 64 + i * 16 + g * 4 + r;
        int col = n0 + wn * 32 + j * 16 + li;
        float v = acc[i][j][r] + bcol[j];
        if (RELU) v = fmaxf(v, 0.f);
        out[(size_t)row * N + col] = v;
      }
    }
  }
}

// ------- Flash attention: swapped-QK^T, fragment-packed QKV, 4-way K-split,
// TWO independent (m,l,o) chains per wave (T15 ILP: chain A = kt, kt+8, ...;
// chain B = kt+4, kt+12, ...). Chains merge in-wave (exact common-max) before
// the existing 4-wave LDS merge. -------
#define ATILE(KT, MRUN, LRUN, OO0, OO1) do {                                   \
    const int kt = (KT);                                                       \
    const bool kh1 = (kt * 64 + 32 <= wq0 + 31);                               \
    const bool domask = (kt * 64 + (kh1 ? 63 : 31) > wq0);                     \
    const u16* kb_ = kbase + ((size_t)kt << 12);                               \
    const u16* vb_ = vbase + ((size_t)kt << 12);                               \
    bf16x8 kf0[4], kf1[4];                                                     \
    _Pragma("unroll")                                                          \
    for (int d4 = 0; d4 < 4; ++d4) {                                           \
      kf0[d4] = *(const bf16x8*)(kb_ + ((d4 * 2 + 0) << 9));                   \
      if (kh1) kf1[d4] = *(const bf16x8*)(kb_ + ((d4 * 2 + 1) << 9));          \
    }                                                                          \
    bf16x8 vf0[4], vf1[4];                                                     \
    _Pragma("unroll")                                                          \
    for (int t = 0; t < 4; ++t)                                                \
      if (t < 2 || kh1) {                                                      \
        vf0[t] = *(const bf16x8*)(vb_ + ((t * 2 + 0) << 9));                   \
        vf1[t] = *(const bf16x8*)(vb_ + ((t * 2 + 1) << 9));                   \
      }                                                                        \
    f32x16 S0 = {}, S1 = {};                                                   \
    _Pragma("unroll")                                                          \
    for (int d4 = 0; d4 < 4; ++d4)                                             \
      S0 = __builtin_amdgcn_mfma_f32_32x32x16_bf16(kf0[d4], qf[d4], S0, 0, 0, 0); \
    if (kh1) {                                                                 \
      _Pragma("unroll")                                                        \
      for (int d4 = 0; d4 < 4; ++d4)                                           \
        S1 = __builtin_amdgcn_mfma_f32_32x32x16_bf16(kf1[d4], qf[d4], S1, 0, 0, 0); \
    }                                                                          \
    if (domask) {                                                              \
      const int qrel = qg - kt * 64 - 4 * hl;                                  \
      _Pragma("unroll")                                                        \
      for (int r = 0; r < 16; ++r) {                                           \
        const int kc = (r & 3) + 8 * (r >> 2);                                 \
        S0[r] = (kc <= qrel) ? S0[r] : -3.0e38f;                               \
      }                                                                        \
      if (kh1) {                                                               \
        _Pragma("unroll")                                                      \
        for (int r = 0; r < 16; ++r) {                                         \
          const int kc = 32 + (r & 3) + 8 * (r >> 2);                          \
          S1[r] = (kc <= qrel) ? S1[r] : -3.0e38f;                             \
        }                                                                      \
      }                                                                        \
    }                                                                          \
    float mt = -3.0e38f;                                                       \
    _Pragma("unroll")                                                          \
    for (int r = 0; r < 16; ++r) mt = fmaxf(mt, S0[r]);                        \
    if (kh1) {                                                                 \
      _Pragma("unroll")                                                        \
      for (int r = 0; r < 16; ++r) mt = fmaxf(mt, S1[r]);                      \
    }                                                                          \
    mt = fmaxf(mt, __shfl_xor(mt, 32, 64));                                    \
    if (!__all(mt <= MRUN + 8.0f)) {                                           \
      const float mn = fmaxf(MRUN, mt);                                        \
      const float alpha = exp2f(MRUN - mn);                                    \
      LRUN *= alpha;                                                           \
      OO0 *= alpha;                                                            \
      OO1 *= alpha;                                                            \
      MRUN = mn;                                                               \
    }                                                                          \
    float sum = 0.f;                                                           \
    _Pragma("unroll")                                                          \
    for (int r = 0; r < 16; ++r) { S0[r] = exp2f(S0[r] - MRUN); sum += S0[r]; }\
    if (kh1) {                                                                 \
      _Pragma("unroll")                                                        \
      for (int r = 0; r < 16; ++r) { S1[r] = exp2f(S1[r] - MRUN); sum += S1[r]; } \
    }                                                                          \
    sum += __shfl_xor(sum, 32, 64);                                            \
    LRUN += sum;                                                               \
    u32 pk[2][8], sw[2][8];                                                    \
    _Pragma("unroll")                                                          \
    for (int m = 0; m < 4; ++m) {                                              \
      asm("v_cvt_pk_bf16_f32 %0, %1, %2" : "=v"(pk[0][2*m])   : "v"(S0[4*m+0]), "v"(S0[4*m+1])); \
      asm("v_cvt_pk_bf16_f32 %0, %1, %2" : "=v"(pk[0][2*m+1]) : "v"(S0[4*m+2]), "v"(S0[4*m+3])); \
    }                                                                          \
    _Pragma("unroll")                                                          \
    for (int i = 0; i < 8; ++i) sw[0][i] = __shfl_xor(pk[0][i], 32, 64);       \
    if (kh1) {                                                                 \
      _Pragma("unroll")                                                        \
      for (int m = 0; m < 4; ++m) {                                            \
        asm("v_cvt_pk_bf16_f32 %0, %1, %2" : "=v"(pk[1][2*m])   : "v"(S1[4*m+0]), "v"(S1[4*m+1])); \
        asm("v_cvt_pk_bf16_f32 %0, %1, %2" : "=v"(pk[1][2*m+1]) : "v"(S1[4*m+2]), "v"(S1[4*m+3])); \
      }                                                                        \
      _Pragma("unroll")                                                        \
      for (int i = 0; i < 8; ++i) sw[1][i] = __shfl_xor(pk[1][i], 32, 64);     \
    }                                                                          \
    _Pragma("unroll")                                                          \
    for (int t = 0; t < 4; ++t) {                                              \
      if (t < 2 || kh1) {                                                      \
        const int cq = t >> 1, mq0 = 2 * (t & 1), mq1 = mq0 + 1;               \
        union { u32 u[4]; bf16x8 v; } pf;                                      \
        pf.u[0] = hl ? sw[cq][2*mq1]   : pk[cq][2*mq0];                        \
        pf.u[1] = hl ? sw[cq][2*mq1+1] : pk[cq][2*mq0+1];                      \
        pf.u[2] = hl ? pk[cq][2*mq1]   : sw[cq][2*mq0];                        \
        pf.u[3] = hl ? pk[cq][2*mq1+1] : sw[cq][2*mq0+1];                      \
        OO0 = __builtin_amdgcn_mfma_f32_32x32x16_bf16(vf0[t], pf.v, OO0, 0, 0, 0); \
        OO1 = __builtin_amdgcn_mfma_f32_32x32x16_bf16(vf1[t], pf.v, OO1, 0, 0, 0); \
      }                                                                        \
    }                                                                          \
  } while (0)

__global__ __launch_bounds__(256, 2) void k_attn8(
    const u16* __restrict__ Qp, const u16* __restrict__ Kp,
    const u16* __restrict__ Vp, u16* __restrict__ ctx) {
  const int bh = blockIdx.x;
  const int t32 = 63 - (int)blockIdx.y;            // largest first
  const int b = bh >> 4, h = bh & 15;
  const int tid = threadIdx.x;
  const int wid = tid >> 6, lane = tid & 63;
  const int ql = lane & 31, hl = lane >> 5;

  __shared__ __align__(16) float mrg[3][64][34];

  const int wq0 = t32 * 32;
  const int qg = wq0 + ql;
  const int nt = ((wq0 + 31) >> 6) + 1;            // 64-wide k-tiles

  bf16x8 qf[4];
  {
    const u16* qpb = Qp + ((((size_t)bh * 64 + t32) * 4) << 9) + lane * 8;
    #pragma unroll
    for (int d4 = 0; d4 < 4; ++d4)
      qf[d4] = *(const bf16x8*)(qpb + (d4 << 9));
  }

  const u16* kbase = Kp + (((size_t)bh * 32) << 12) + lane * 8;  // +kt*4096
  const u16* vbase = Vp + (((size_t)bh * 32) << 12) + lane * 8;

  // two independent chains per wave
  f32x16 oA0 = {}, oA1 = {}, oB0 = {}, oB1 = {};
  float mA = -1e30f, lA = 0.f, mB = -1e30f, lB = 0.f;

  for (int kt2 = wid; kt2 < nt; kt2 += 8) {
    ATILE(kt2, mA, lA, oA0, oA1);
    if (kt2 + 4 < nt) ATILE(kt2 + 4, mB, lB, oB0, oB1);
  }

  // in-wave chain merge (exact, common max)
  {
    const float Mw = fmaxf(mA, mB);
    const float fA = exp2f(mA - Mw), fB = exp2f(mB - Mw);
    oA0 = oA0 * fA + oB0 * fB;
    oA1 = oA1 * fA + oB1 * fB;
    lA = lA * fA + lB * fB;
    mA = Mw;
  }

  if (wid > 0) {
    float* pq = &mrg[wid - 1][lane][0];
    *(f32x16*)(pq) = oA0;
    *(f32x16*)(pq + 16) = oA1;
    pq[32] = mA;
    pq[33] = lA;
  }
  __syncthreads();
  if (wid > 0) return;

  float M = mA;
  #pragma unroll
  for (int w = 0; w < 3; ++w) M = fmaxf(M, mrg[w][lane][32]);
  const float fa = exp2f(mA - M);
  f32x16 acc0 = oA0 * fa, acc1 = oA1 * fa;
  float L = lA * fa;
  #pragma unroll
  for (int w = 0; w < 3; ++w) {
    const float* pq = &mrg[w][lane][0];
    const float fw = exp2f(pq[32] - M);
    L += pq[33] * fw;
    f32x16 t0 = *(const f32x16*)(pq);
    f32x16 t1 = *(const f32x16*)(pq + 16);
    acc0 += t0 * fw;
    acc1 += t1 * fw;
  }
  const float inv = 1.f / L;

  u16* outp = ctx + (size_t)(b * SEQ + qg) * EMBED + h * HDIM + 4 * hl;
  #pragma unroll
  for (int m = 0; m < 4; ++m) {
    ushort4 s0v, s1v;
    s0v.x = f2bf(acc0[4*m+0] * inv); s0v.y = f2bf(acc0[4*m+1] * inv);
    s0v.z = f2bf(acc0[4*m+2] * inv); s0v.w = f2bf(acc0[4*m+3] * inv);
    *(ushort4*)(outp + 8 * m) = s0v;
    s1v.x = f2bf(acc1[4*m+0] * inv); s1v.y = f2bf(acc1[4*m+1] * inv);
    s1v.z = f2bf(acc1[4*m+2] * inv); s1v.w = f2bf(acc1[4*m+3] * inv);
    *(ushort4*)(outp + 32 + 8 * m) = s1v;
  }
}
#undef ATILE

// ---------------- fused residual-add + LayerNorm ----------------
__global__ __launch_bounds__(256) void k_add_ln(
    const float* __restrict__ a, const float* __restrict__ bmat,
    const float* __restrict__ gam, const float* __restrict__ bet,
    float* __restrict__ outf, u16* __restrict__ outb) {
  const int row = blockIdx.x;
  const int t = threadIdx.x;
  __shared__ float red[8];
  float4 va = ((const float4*)(a + (size_t)row * EMBED))[t];
  float4 vb = ((const float4*)(bmat + (size_t)row * EMBED))[t];
  float s0 = va.x + vb.x, s1 = va.y + vb.y, s2 = va.z + vb.z, s3 = va.w + vb.w;
  float sum = s0 + s1 + s2 + s3;
  float sq = s0 * s0 + s1 * s1 + s2 * s2 + s3 * s3;
  #pragma unroll
  for (int m = 1; m < 64; m <<= 1) {
    sum += __shfl_xor(sum, m, 64);
    sq += __shfl_xor(sq, m, 64);
  }
  int wid = t >> 6;
  if ((t & 63) == 0) { red[wid] = sum; red[4 + wid] = sq; }
  __syncthreads();
  sum = red[0] + red[1] + red[2] + red[3];
  sq = red[4] + red[5] + red[6] + red[7];
  float mean = sum * (1.f / EMBED);
  float var = sq * (1.f / EMBED) - mean * mean;
  float rstd = rsqrtf(var + 1e-5f);
  float4 gv = ((const float4*)gam)[t], bev = ((const float4*)bet)[t];
  float y0 = (s0 - mean) * rstd * gv.x + bev.x;
  float y1 = (s1 - mean) * rstd * gv.y + bev.y;
  float y2 = (s2 - mean) * rstd * gv.z + bev.z;
  float y3 = (s3 - mean) * rstd * gv.w + bev.w;
  if (outf) {
    float4 o; o.x = y0; o.y = y1; o.z = y2; o.w = y3;
    ((float4*)(outf + (size_t)row * EMBED))[t] = o;
  }
  if (outb) {
    ushort4 ob; ob.x = f2bf(y0); ob.y = f2bf(y1); ob.z = f2bf(y2); ob.w = f2bf(y3);
    ((ushort4*)(outb + (size_t)row * EMBED))[t] = ob;
  }
}

// ------- fused 4-partial split-K combine + residual + bias + LayerNorm -------
__global__ __launch_bounds__(256) void k_add_ln4(
    const float* __restrict__ a, const float* __restrict__ parts,
    const float* __restrict__ bias,
    const float* __restrict__ gam, const float* __restrict__ bet,
    float* __restrict__ outf) {
  const int row = blockIdx.x;
  const int t = threadIdx.x;
  __shared__ float red[8];
  float4 va = ((const float4*)(a + (size_t)row * EMBED))[t];
  float4 bv = ((const float4*)bias)[t];
  float s0 = va.x + bv.x, s1 = va.y + bv.y, s2 = va.z + bv.z, s3 = va.w + bv.w;
  #pragma unroll
  for (int c = 0; c < 4; ++c) {
    float4 pv = ((const float4*)(parts + (size_t)c * MTOT * EMBED + (size_t)row * EMBED))[t];
    s0 += pv.x; s1 += pv.y; s2 += pv.z; s3 += pv.w;
  }
  float sum = s0 + s1 + s2 + s3;
  float sq = s0 * s0 + s1 * s1 + s2 * s2 + s3 * s3;
  #pragma unroll
  for (int m = 1; m < 64; m <<= 1) {
    sum += __shfl_xor(sum, m, 64);
    sq += __shfl_xor(sq, m, 64);
  }
  int wid = t >> 6;
  if ((t & 63) == 0) { red[wid] = sum; red[4 + wid] = sq; }
  __syncthreads();
  sum = red[0] + red[1] + red[2] + red[3];
  sq = red[4] + red[5] + red[6] + red[7];
  float mean = sum * (1.f / EMBED);
  float var = sq * (1.f / EMBED) - mean * mean;
  float rstd = rsqrtf(var + 1e-5f);
  float4 gv = ((const float4*)gam)[t], bev = ((const float4*)bet)[t];
  float4 o;
  o.x = (s0 - mean) * rstd * gv.x + bev.x;
  o.y = (s1 - mean) * rstd * gv.y + bev.y;
  o.z = (s2 - mean) * rstd * gv.z + bev.z;
  o.w = (s3 - mean) * rstd * gv.w + bev.w;
  ((float4*)(outf + (size_t)row * EMBED))[t] = o;
}

extern "C" void kernel_launch(void* const* d_in, const int* in_sizes, int n_in,
                              void* d_out, int out_size, void* d_ws, size_t ws_size,
                              hipStream_t stream) {
  const float* x      = (const float*)d_in[0];
  const float* w_qkv  = (const float*)d_in[1];
  const float* b_qkv  = (const float*)d_in[2];
  const float* w_out  = (const float*)d_in[3];
  const float* b_out  = (const float*)d_in[4];
  const float* w_up   = (const float*)d_in[5];
  const float* b_up   = (const float*)d_in[6];
  const float* w_down = (const float*)d_in[7];
  const float* b_down = (const float*)d_in[8];
  const float* g1  = (const float*)d_in[9];
  const float* be1 = (const float*)d_in[10];
  const float* g2  = (const float*)d_in[11];
  const float* be2 = (const float*)d_in[12];

  char* ws = (char*)d_ws;
  size_t off = 0;
  auto alloc = [&](size_t bytes) { void* p = ws + off; off += (bytes + 255) & ~(size_t)255; return p; };

  u16* xb     = (u16*)alloc((size_t)MTOT * EMBED * 2);
  u16* wqkvT  = (u16*)alloc((size_t)3 * EMBED * EMBED * 2);
  u16* woutT  = (u16*)alloc((size_t)EMBED * EMBED * 2);
  u16* wupT   = (u16*)alloc((size_t)FFN * EMBED * 2);
  u16* wdownT = (u16*)alloc((size_t)EMBED * FFN * 2);
  u16* qp     = (u16*)alloc((size_t)MTOT * EMBED * 2);   // fragment-packed Q
  u16* kp     = (u16*)alloc((size_t)MTOT * EMBED * 2);   // fragment-packed K
  u16* vp     = (u16*)alloc((size_t)MTOT * EMBED * 2);   // fragment-packed V
  u16* ctx    = (u16*)alloc((size_t)MTOT * EMBED * 2);
  float* attn_proj = (float*)alloc((size_t)MTOT * EMBED * 4);
  float* y_f32     = (float*)alloc((size_t)MTOT * EMBED * 4);
  u16* y_bf16      = (u16*)alloc((size_t)MTOT * EMBED * 2);
  u16* hmid        = (u16*)alloc((size_t)MTOT * FFN * 2);
  float* fparts    = (float*)alloc((size_t)4 * MTOT * EMBED * 4);  // down-proj split-K partials

  dim3 trb(32, 8);
  k_cvt<<<2048, 256, 0, stream>>>(x, xb, MTOT * EMBED / 4);
  k_tr<<<dim3(3 * EMBED / 32, EMBED / 32), trb, 0, stream>>>(w_qkv, wqkvT, EMBED, 3 * EMBED);
  k_tr<<<dim3(EMBED / 32, EMBED / 32), trb, 0, stream>>>(w_out, woutT, EMBED, EMBED);
  k_tr<<<dim3(FFN / 32, EMBED / 32), trb, 0, stream>>>(w_up, wupT, EMBED, FFN);
  k_tr<<<dim3(EMBED / 32, FFN / 32), trb, 0, stream>>>(w_down, wdownT, FFN, EMBED);

  k_gemm8<2, false><<<dim3(3 * EMBED / 256, MTOT / 256), 512, 0, stream>>>(
      xb, wqkvT, b_qkv, qp, kp, vp, MTOT, 3 * EMBED, EMBED, EMBED);

  k_attn8<<<dim3(BATCH * HEADS, 64), 256, 0, stream>>>(qp, kp, vp, ctx);

  k_gemmD<false><<<dim3(EMBED / 128, MTOT / 128), 512, 0, stream>>>(
      ctx, woutT, b_out, attn_proj, MTOT, EMBED, EMBED);

  k_add_ln<<<MTOT, 256, 0, stream>>>(x, attn_proj, g1, be1, y_f32, y_bf16);

  k_gemm8<0, true><<<dim3(FFN / 256, MTOT / 256), 512, 0, stream>>>(
      y_bf16, wupT, b_up, hmid, nullptr, nullptr, MTOT, FFN, EMBED, EMBED);

  k_gemm8<3, false><<<dim3(EMBED / 256, MTOT / 256, 4), 512, 0, stream>>>(
      hmid, wdownT, nullptr, fparts, nullptr, nullptr, MTOT, EMBED, FFN / 4, FFN);

  k_add_ln4<<<MTOT, 256, 0, stream>>>(y_f32, fparts, b_down, g2, be2, (float*)d_out);

  (void)in_sizes; (void)n_in; (void)out_size; (void)ws_size;
}

// Round 22
// 228.816 us; speedup vs baseline: 1.0303x; 1.0303x over previous
//
#include <hip/hip_runtime.h>
#include <hip/hip_bf16.h>

#define EMBED 1024
#define HEADS 16
#define HDIM 64
#define FFN 4096
#define SEQ 2048
#define BATCH 2
#define MTOT (BATCH*SEQ)
#define QSCALE 0.1803368801111137f   // 0.125 * log2(e)

typedef __attribute__((ext_vector_type(8))) short bf16x8;
typedef __attribute__((ext_vector_type(4))) float f32x4;
typedef __attribute__((ext_vector_type(16))) float f32x16;
typedef unsigned short u16;
typedef unsigned int u32;

__device__ __forceinline__ u16 f2bf(float f) {
  union { float f; unsigned u; } v; v.f = f;
  unsigned r = v.u + 0x7FFFu + ((v.u >> 16) & 1u);
  return (u16)(r >> 16);
}

__device__ __forceinline__ void async_ld16(const void* g, void* l) {
  __builtin_amdgcn_global_load_lds((const __attribute__((address_space(1))) void*)g,
                                   (__attribute__((address_space(3))) void*)l,
                                   16, 0, 0);
}

// QKV scatter into MFMA-fragment-major layouts (coalesced attention loads).
__device__ __forceinline__ void qkv_scatter(u16* qp, u16* kp, u16* vp,
                                            int row, int col, float v) {
  const int which = col >> 10, hh = (col >> 6) & 15, d = col & 63;
  const int bb = row >> 11, ss = row & 2047;
  const int bh = bb * 16 + hh;
  if (which == 0) {
    v *= QSCALE;
    size_t idx = ((((size_t)bh * 64 + (ss >> 5)) * 4 + (d >> 4)) << 9)
               + (((ss & 31) + 32 * ((d >> 3) & 1)) << 3) + (d & 7);
    qp[idx] = f2bf(v);
  } else if (which == 1) {
    size_t idx = ((((size_t)bh * 32 + (ss >> 6)) * 8 + (d >> 4) * 2 + ((ss >> 5) & 1)) << 9)
               + (((ss & 31) + 32 * ((d >> 3) & 1)) << 3) + (d & 7);
    kp[idx] = f2bf(v);
  } else {
    size_t idx = ((((size_t)bh * 32 + (ss >> 6)) * 8 + ((ss & 63) >> 4) * 2 + (d >> 5)) << 9)
               + (((d & 31) + 32 * ((ss >> 3) & 1)) << 3) + (ss & 7);
    vp[idx] = f2bf(v);
  }
}

// ---------------- fp32 -> bf16 convert (vectorized) ----------------
__global__ __launch_bounds__(256) void k_cvt(const float* __restrict__ in,
                                             u16* __restrict__ out, int n4) {
  int i = blockIdx.x * 256 + threadIdx.x;
  int st = gridDim.x * 256;
  for (; i < n4; i += st) {
    float4 v = ((const float4*)in)[i];
    ushort4 o;
    o.x = f2bf(v.x); o.y = f2bf(v.y); o.z = f2bf(v.z); o.w = f2bf(v.w);
    ((ushort4*)out)[i] = o;
  }
}

// ---------------- transpose-convert: w[K,N] fp32 -> wT[N,K] bf16 ----------------
__global__ __launch_bounds__(256) void k_tr(const float* __restrict__ w,
                                            u16* __restrict__ wT, int K, int N) {
  __shared__ u16 tile[32][33];
  int n0 = blockIdx.x * 32, k0 = blockIdx.y * 32;
  int tx = threadIdx.x, ty = threadIdx.y;   // blockDim (32,8)
  #pragma unroll
  for (int i = 0; i < 4; ++i) {
    int k = k0 + ty + i * 8;
    tile[ty + i * 8][tx] = f2bf(w[(size_t)k * N + n0 + tx]);
  }
  __syncthreads();
  #pragma unroll
  for (int i = 0; i < 4; ++i) {
    int n = n0 + ty + i * 8;
    wT[(size_t)n * K + k0 + tx] = tile[tx][ty + i * 8];
  }
}

// ======== 8-phase 256x256 GEMM: counted vmcnt, one barrier/phase, =========
// quadrant order (0,0)->(1,0)->(1,1)->(0,1) with register-cached shared
// fragments. Stage issue A0@P1,B0@P2,A1@P3,B1@P4; gates VM4,VM4,-,VM4.
template <int OMODE, bool RELU>
__global__ __launch_bounds__(512) void k_gemm8(
    const u16* __restrict__ A, const u16* __restrict__ BT,
    const float* __restrict__ bias,
    void* __restrict__ out0, void* __restrict__ out1, void* __restrict__ out2,
    int M, int N, int K, int ldk) {
  __shared__ __align__(16) u16 As[2][2][128 * 64];
  __shared__ __align__(16) u16 Bs[2][2][128 * 64];
  const int tid = threadIdx.x;
  const int lane = tid & 63, g = lane >> 4, li = lane & 15;
  const int wid = tid >> 6, wm = wid >> 2, wn = wid & 3;

  const int gx = gridDim.x;
  const int nwg = gx * gridDim.y;
  const int flat = blockIdx.y * gx + blockIdx.x;
  const int cpx = nwg >> 3;
  const int swz = (flat & 7) * cpx + (flat >> 3);
  const int m0 = (swz / gx) * 256, n0 = (swz % gx) * 256;
  const int kchunk = blockIdx.z * K;

  f32x4 acc[8][4] = {};

  const u16* Ablk = A + (size_t)m0 * ldk + kchunk;
  const u16* Bblk = BT + (size_t)n0 * ldk + kchunk;
  const int trow = tid >> 3;                    // 0..63
  const int sc = (tid & 7) ^ (trow & 7);        // swizzled source chunk

  auto stageA = [&](int buf, int h, int kt) {
    #pragma unroll
    for (int r = 0; r < 2; ++r)
      async_ld16(Ablk + (size_t)(h * 64 + r * 128 + trow) * ldk + kt + sc * 8,
                 &As[buf][h][0] + r * 4096 + tid * 8);
  };
  auto stageB = [&](int buf, int h, int kt) {
    #pragma unroll
    for (int r = 0; r < 2; ++r) {
      const int p = trow + r * 64;
      async_ld16(Bblk + (size_t)(((p >> 5) << 6) + h * 32 + (p & 31)) * ldk + kt + sc * 8,
                 &Bs[buf][h][0] + r * 4096 + tid * 8);
    }
  };

#define VM4_ asm volatile("s_waitcnt vmcnt(4)" ::: "memory")
#define VM2_ asm volatile("s_waitcnt vmcnt(2)" ::: "memory")
#define VM0_ asm volatile("s_waitcnt vmcnt(0)" ::: "memory")
#define VMN_
#define GP8(IH, JH, READA, READB, VMSTMT, STAGE_STMT) do {                     \
    if (READA) {                                                               \
      _Pragma("unroll")                                                        \
      for (int i2 = 0; i2 < 4; ++i2) {                                         \
        const int pa = wm * 64 + i2 * 16 + li;                                 \
        _Pragma("unroll")                                                      \
        for (int ks = 0; ks < 2; ++ks)                                         \
          a_[i2][ks] = *(const bf16x8*)(&As[cur][IH][0] + pa * 64 +            \
                                        (((ks * 4 + g) ^ (li & 7)) * 8));      \
      }                                                                        \
    }                                                                          \
    if (READB) {                                                               \
      _Pragma("unroll")                                                        \
      for (int j2 = 0; j2 < 2; ++j2) {                                         \
        const int pb = wn * 32 + j2 * 16 + li;                                 \
        _Pragma("unroll")                                                      \
        for (int ks = 0; ks < 2; ++ks)                                         \
          b_[j2][ks] = *(const bf16x8*)(&Bs[cur][JH][0] + pb * 64 +            \
                                        (((ks * 4 + g) ^ (li & 7)) * 8));      \
      }                                                                        \
    }                                                                          \
    STAGE_STMT;                                                                \
    VMSTMT;                                                                    \
    __builtin_amdgcn_s_barrier();                                              \
    asm volatile("s_waitcnt lgkmcnt(0)" ::: "memory");                         \
    __builtin_amdgcn_sched_barrier(0);                                         \
    __builtin_amdgcn_s_setprio(1);                                             \
    _Pragma("unroll")                                                          \
    for (int ks = 0; ks < 2; ++ks)                                             \
      _Pragma("unroll")                                                        \
      for (int i2 = 0; i2 < 4; ++i2)                                           \
        _Pragma("unroll")                                                      \
        for (int j2 = 0; j2 < 2; ++j2)                                         \
          acc[IH * 4 + i2][JH * 2 + j2] = __builtin_amdgcn_mfma_f32_16x16x32_bf16( \
              a_[i2][ks], b_[j2][ks], acc[IH * 4 + i2][JH * 2 + j2], 0, 0, 0); \
    __builtin_amdgcn_s_setprio(0);                                             \
    asm volatile("" ::: "memory");                                             \
  } while (0)

  stageA(0, 0, 0); stageB(0, 0, 0); stageA(0, 1, 0); stageB(0, 1, 0);
  VM4_;   // A0,B0 of tile 0 done
  __builtin_amdgcn_s_barrier();
  asm volatile("" ::: "memory");

  int cur = 0;
  const int nkt = K >> 6;
  bf16x8 a_[4][2], b_[2][2];
  for (int t = 0; t < nkt - 1; ++t) {
    const int kn = (t + 1) * 64;
    GP8(0, 0, 1, 1, VM4_, stageA(cur ^ 1, 0, kn));   // gate: A1(t) done
    GP8(1, 0, 1, 0, VM4_, stageB(cur ^ 1, 0, kn));   // gate: B1(t) done
    GP8(1, 1, 0, 1, VMN_, stageA(cur ^ 1, 1, kn));
    GP8(0, 1, 1, 0, VM4_, stageB(cur ^ 1, 1, kn));   // gate: A0,B0(t+1) done
    cur ^= 1;
  }
  GP8(0, 0, 1, 1, VM2_, );
  GP8(1, 0, 1, 0, VM0_, );
  GP8(1, 1, 0, 1, VMN_, );
  GP8(0, 1, 1, 0, VMN_, );
#undef GP8
#undef VM4_
#undef VM2_
#undef VM0_
#undef VMN_

  float bcol[4];
  #pragma unroll
  for (int j = 0; j < 4; ++j)
    bcol[j] = (OMODE == 3) ? 0.f : bias[n0 + wn * 64 + j * 16 + li];

  #pragma unroll
  for (int i = 0; i < 8; ++i) {
    #pragma unroll
    for (int j = 0; j < 4; ++j) {
      #pragma unroll
      for (int r = 0; r < 4; ++r) {
        int row = m0 + wm * 128 + i * 16 + g * 4 + r;
        int col = n0 + wn * 64 + j * 16 + li;
        float v = acc[i][j][r] + bcol[j];
        if (RELU) v = fmaxf(v, 0.f);
        if (OMODE == 0) {
          ((u16*)out0)[(size_t)row * N + col] = f2bf(v);
        } else if (OMODE == 3) {
          ((float*)out0)[(size_t)blockIdx.z * M * N + (size_t)row * N + col] = v;
        } else {
          qkv_scatter((u16*)out0, (u16*)out1, (u16*)out2, row, col, v);
        }
      }
    }
  }
}

// ===== k_gemmD: 128x128 GEMM for the N=1024 out-proj. 8 waves, BK=64, =====
// 2 phases/K-tile, 4 LDS buffers, stage 2 ahead, counted vmcnt gates,
// one barrier per phase.
template <bool RELU>
__global__ __launch_bounds__(512) void k_gemmD(
    const u16* __restrict__ A, const u16* __restrict__ BT,
    const float* __restrict__ bias, float* __restrict__ out,
    int M, int N, int K) {
  __shared__ __align__(16) u16 As[4][2][64 * 64];
  __shared__ __align__(16) u16 Bs[4][2][64 * 64];
  const int tid = threadIdx.x;
  const int lane = tid & 63, g = lane >> 4, li = lane & 15;
  const int wid = tid >> 6, wm = wid >> 2, wn = wid & 3;

  const int gx = gridDim.x;
  const int nwg = gx * gridDim.y;
  const int flat = blockIdx.y * gx + blockIdx.x;
  const int cpx = nwg >> 3;
  const int swz = (flat & 7) * cpx + (flat >> 3);
  const int m0 = (swz / gx) * 128, n0 = (swz % gx) * 128;

  f32x4 acc[4][2] = {};

  const u16* Ablk = A + (size_t)m0 * K;
  const u16* Bblk = BT + (size_t)n0 * K;
  const int p = tid >> 3;
  const int c = (tid & 7) ^ (p & 7);

  auto stageAll = [&](int buf, int kt) {
    {
      const int grow = (p >> 5) * 64 + 0 * 32 + (p & 31);
      async_ld16(Ablk + (size_t)grow * K + kt + c * 8, &As[buf][0][0] + tid * 8);
    }
    {
      const int grow = (p >> 4) * 32 + 0 * 16 + (p & 15);
      async_ld16(Bblk + (size_t)grow * K + kt + c * 8, &Bs[buf][0][0] + tid * 8);
    }
    {
      const int grow = (p >> 4) * 32 + 1 * 16 + (p & 15);
      async_ld16(Bblk + (size_t)grow * K + kt + c * 8, &Bs[buf][1][0] + tid * 8);
    }
    {
      const int grow = (p >> 5) * 64 + 1 * 32 + (p & 31);
      async_ld16(Ablk + (size_t)grow * K + kt + c * 8, &As[buf][1][0] + tid * 8);
    }
  };

#define GATE(n) asm volatile("s_waitcnt vmcnt(" #n ")" ::: "memory")
  stageAll(0, 0);
  stageAll(1, 64);
  GATE(5);
  __builtin_amdgcn_s_barrier();
  asm volatile("" ::: "memory");

  const int nkt = K >> 6;
  const int pa0 = wm * 32 + li, pa1 = wm * 32 + 16 + li;
  const int pb = wn * 16 + li;
  for (int t = 0; t < nkt; ++t) {
    const int buf = t & 3;
    bf16x8 a_[2][2], b_[2][2];
    #pragma unroll
    for (int ks = 0; ks < 2; ++ks) {
      a_[0][ks] = *(const bf16x8*)(&As[buf][0][0] + pa0 * 64 + (((ks * 4 + g) ^ (pa0 & 7)) * 8));
      a_[1][ks] = *(const bf16x8*)(&As[buf][0][0] + pa1 * 64 + (((ks * 4 + g) ^ (pa1 & 7)) * 8));
      b_[0][ks] = *(const bf16x8*)(&Bs[buf][0][0] + pb * 64 + (((ks * 4 + g) ^ (pb & 7)) * 8));
      b_[1][ks] = *(const bf16x8*)(&Bs[buf][1][0] + pb * 64 + (((ks * 4 + g) ^ (pb & 7)) * 8));
    }
    if (t + 2 < nkt) {
      stageAll((t + 2) & 3, (t + 2) * 64);
      GATE(8);
    } else if (t + 1 < nkt) {
      GATE(4);
    } else {
      GATE(0);
    }
    __builtin_amdgcn_s_barrier();
    asm volatile("s_waitcnt lgkmcnt(0)" ::: "memory");
    __builtin_amdgcn_sched_barrier(0);
    __builtin_amdgcn_s_setprio(1);
    #pragma unroll
    for (int ks = 0; ks < 2; ++ks)
      #pragma unroll
      for (int i2l = 0; i2l < 2; ++i2l)
        #pragma unroll
        for (int j2 = 0; j2 < 2; ++j2)
          acc[i2l][j2] = __builtin_amdgcn_mfma_f32_16x16x32_bf16(
              a_[i2l][ks], b_[j2][ks], acc[i2l][j2], 0, 0, 0);
    __builtin_amdgcn_s_setprio(0);
    asm volatile("" ::: "memory");
    #pragma unroll
    for (int ks = 0; ks < 2; ++ks) {
      a_[0][ks] = *(const bf16x8*)(&As[buf][1][0] + pa0 * 64 + (((ks * 4 + g) ^ (pa0 & 7)) * 8));
      a_[1][ks] = *(const bf16x8*)(&As[buf][1][0] + pa1 * 64 + (((ks * 4 + g) ^ (pa1 & 7)) * 8));
    }
    if (t + 2 < nkt)      GATE(5);
    else if (t + 1 < nkt) GATE(1);
    __builtin_amdgcn_s_barrier();
    asm volatile("s_waitcnt lgkmcnt(0)" ::: "memory");
    __builtin_amdgcn_sched_barrier(0);
    __builtin_amdgcn_s_setprio(1);
    #pragma unroll
    for (int ks = 0; ks < 2; ++ks)
      #pragma unroll
      for (int i2l = 0; i2l < 2; ++i2l)
        #pragma unroll
        for (int j2 = 0; j2 < 2; ++j2)
          acc[2 + i2l][j2] = __builtin_amdgcn_mfma_f32_16x16x32_bf16(
              a_[i2l][ks], b_[j2][ks], acc[2 + i2l][j2], 0, 0, 0);
    __builtin_amdgcn_s_setprio(0);
    asm volatile("" ::: "memory");
  }
#undef GATE

  float bcol[2];
  #pragma unroll
  for (int j = 0; j < 2; ++j) bcol[j] = bias[n0 + wn * 32 + j * 16 + li];

  #pragma unroll
  for (int i = 0; i < 4; ++i) {
    #pragma unroll
    for (int j = 0; j < 2; ++j) {
      #pragma unroll
      for (int r = 0; r < 4; ++r) {
        int row = m0 + wm * 64 + i * 16 + g * 4 + r;
        int col = n0 + wn * 32 + j * 16 + li;
        float v = acc[i][j][r] + bcol[j];
        if (RELU) v = fmaxf(v, 0.f);
        out[(size_t)row * N + col] = v;
      }
    }
  }
}

// ------- Flash attention: swapped-QK^T, fragment-packed QKV, 4-way K-split -------
__global__ __launch_bounds__(256, 3) void k_attn7(
    const u16* __restrict__ Qp, const u16* __restrict__ Kp,
    const u16* __restrict__ Vp, u16* __restrict__ ctx) {
  const int bh = blockIdx.x;
  const int t32 = 63 - (int)blockIdx.y;            // largest first
  const int b = bh >> 4, h = bh & 15;
  const int tid = threadIdx.x;
  const int wid = tid >> 6, lane = tid & 63;
  const int ql = lane & 31, hl = lane >> 5;

  __shared__ __align__(16) float mrg[3][64][34];

  const int wq0 = t32 * 32;
  const int qg = wq0 + ql;
  const int nt = ((wq0 + 31) >> 6) + 1;            // 64-wide k-tiles

  bf16x8 qf[4];
  {
    const u16* qpb = Qp + ((((size_t)bh * 64 + t32) * 4) << 9) + lane * 8;
    #pragma unroll
    for (int d4 = 0; d4 < 4; ++d4)
      qf[d4] = *(const bf16x8*)(qpb + (d4 << 9));
  }

  const u16* kbase = Kp + (((size_t)bh * 32) << 12) + lane * 8;  // +kt*4096
  const u16* vbase = Vp + (((size_t)bh * 32) << 12) + lane * 8;

  f32x16 o0 = {}, o1 = {};   // O^T: col q=ql, rows d=(r&3)+8*(r>>2)+4*hl (+32)
  float m_run = -1e30f, l_run = 0.f;

  for (int kt = wid; kt < nt; kt += 4) {
    const bool kh1 = (kt * 64 + 32 <= wq0 + 31);   // wave-uniform
    const bool domask = (kt * 64 + (kh1 ? 63 : 31) > wq0);
    const u16* kb_ = kbase + ((size_t)kt << 12);
    const u16* vb_ = vbase + ((size_t)kt << 12);

    bf16x8 kf0[4], kf1[4];
    #pragma unroll
    for (int d4 = 0; d4 < 4; ++d4) {
      kf0[d4] = *(const bf16x8*)(kb_ + ((d4 * 2 + 0) << 9));
      if (kh1) kf1[d4] = *(const bf16x8*)(kb_ + ((d4 * 2 + 1) << 9));
    }
    bf16x8 vf0[4], vf1[4];
    #pragma unroll
    for (int t = 0; t < 4; ++t)
      if (t < 2 || kh1) {
        vf0[t] = *(const bf16x8*)(vb_ + ((t * 2 + 0) << 9));
        vf1[t] = *(const bf16x8*)(vb_ + ((t * 2 + 1) << 9));
      }

    f32x16 S0 = {}, S1 = {};
    #pragma unroll
    for (int d4 = 0; d4 < 4; ++d4)
      S0 = __builtin_amdgcn_mfma_f32_32x32x16_bf16(kf0[d4], qf[d4], S0, 0, 0, 0);
    if (kh1) {
      #pragma unroll
      for (int d4 = 0; d4 < 4; ++d4)
        S1 = __builtin_amdgcn_mfma_f32_32x32x16_bf16(kf1[d4], qf[d4], S1, 0, 0, 0);
    }

    if (domask) {
      const int qrel = qg - kt * 64 - 4 * hl;
      #pragma unroll
      for (int r = 0; r < 16; ++r) {
        const int kc = (r & 3) + 8 * (r >> 2);
        S0[r] = (kc <= qrel) ? S0[r] : -3.0e38f;
      }
      if (kh1) {
        #pragma unroll
        for (int r = 0; r < 16; ++r) {
          const int kc = 32 + (r & 3) + 8 * (r >> 2);
          S1[r] = (kc <= qrel) ? S1[r] : -3.0e38f;
        }
      }
    }

    float mt = -3.0e38f;
    #pragma unroll
    for (int r = 0; r < 16; ++r) mt = fmaxf(mt, S0[r]);
    if (kh1) {
      #pragma unroll
      for (int r = 0; r < 16; ++r) mt = fmaxf(mt, S1[r]);
    }
    mt = fmaxf(mt, __shfl_xor(mt, 32, 64));

    // defer-max (T13)
    if (!__all(mt <= m_run + 8.0f)) {
      const float mn = fmaxf(m_run, mt);
      const float alpha = exp2f(m_run - mn);
      l_run *= alpha;
      o0 *= alpha;
      o1 *= alpha;
      m_run = mn;
    }
    float sum = 0.f;
    #pragma unroll
    for (int r = 0; r < 16; ++r) { S0[r] = exp2f(S0[r] - m_run); sum += S0[r]; }
    if (kh1) {
      #pragma unroll
      for (int r = 0; r < 16; ++r) { S1[r] = exp2f(S1[r] - m_run); sum += S1[r]; }
    }
    sum += __shfl_xor(sum, 32, 64);
    l_run += sum;

    u32 pk[2][8], sw[2][8];
    #pragma unroll
    for (int m = 0; m < 4; ++m) {
      asm("v_cvt_pk_bf16_f32 %0, %1, %2" : "=v"(pk[0][2*m])   : "v"(S0[4*m+0]), "v"(S0[4*m+1]));
      asm("v_cvt_pk_bf16_f32 %0, %1, %2" : "=v"(pk[0][2*m+1]) : "v"(S0[4*m+2]), "v"(S0[4*m+3]));
    }
    #pragma unroll
    for (int i = 0; i < 8; ++i) sw[0][i] = __shfl_xor(pk[0][i], 32, 64);
    if (kh1) {
      #pragma unroll
      for (int m = 0; m < 4; ++m) {
        asm("v_cvt_pk_bf16_f32 %0, %1, %2" : "=v"(pk[1][2*m])   : "v"(S1[4*m+0]), "v"(S1[4*m+1]));
        asm("v_cvt_pk_bf16_f32 %0, %1, %2" : "=v"(pk[1][2*m+1]) : "v"(S1[4*m+2]), "v"(S1[4*m+3]));
      }
      #pragma unroll
      for (int i = 0; i < 8; ++i) sw[1][i] = __shfl_xor(pk[1][i], 32, 64);
    }

    #pragma unroll
    for (int t = 0; t < 4; ++t) {
      if (t < 2 || kh1) {
        const int c = t >> 1, m0 = 2 * (t & 1), m1 = m0 + 1;
        union { u32 u[4]; bf16x8 v; } pf;
        pf.u[0] = hl ? sw[c][2*m1]   : pk[c][2*m0];
        pf.u[1] = hl ? sw[c][2*m1+1] : pk[c][2*m0+1];
        pf.u[2] = hl ? pk[c][2*m1]   : sw[c][2*m0];
        pf.u[3] = hl ? pk[c][2*m1+1] : sw[c][2*m0+1];
        o0 = __builtin_amdgcn_mfma_f32_32x32x16_bf16(vf0[t], pf.v, o0, 0, 0, 0);
        o1 = __builtin_amdgcn_mfma_f32_32x32x16_bf16(vf1[t], pf.v, o1, 0, 0, 0);
      }
    }
  }

  if (wid > 0) {
    float* pq = &mrg[wid - 1][lane][0];
    *(f32x16*)(pq) = o0;
    *(f32x16*)(pq + 16) = o1;
    pq[32] = m_run;
    pq[33] = l_run;
  }
  __syncthreads();
  if (wid > 0) return;

  float M = m_run;
  #pragma unroll
  for (int w = 0; w < 3; ++w) M = fmaxf(M, mrg[w][lane][32]);
  const float fa = exp2f(m_run - M);
  f32x16 acc0 = o0 * fa, acc1 = o1 * fa;
  float L = l_run * fa;
  #pragma unroll
  for (int w = 0; w < 3; ++w) {
    const float* pq = &mrg[w][lane][0];
    const float fw = exp2f(pq[32] - M);
    L += pq[33] * fw;
    f32x16 t0 = *(const f32x16*)(pq);
    f32x16 t1 = *(const f32x16*)(pq + 16);
    acc0 += t0 * fw;
    acc1 += t1 * fw;
  }
  const float inv = 1.f / L;

  u16* outp = ctx + (size_t)(b * SEQ + qg) * EMBED + h * HDIM + 4 * hl;
  #pragma unroll
  for (int m = 0; m < 4; ++m) {
    ushort4 s0v, s1v;
    s0v.x = f2bf(acc0[4*m+0] * inv); s0v.y = f2bf(acc0[4*m+1] * inv);
    s0v.z = f2bf(acc0[4*m+2] * inv); s0v.w = f2bf(acc0[4*m+3] * inv);
    *(ushort4*)(outp + 8 * m) = s0v;
    s1v.x = f2bf(acc1[4*m+0] * inv); s1v.y = f2bf(acc1[4*m+1] * inv);
    s1v.z = f2bf(acc1[4*m+2] * inv); s1v.w = f2bf(acc1[4*m+3] * inv);
    *(ushort4*)(outp + 32 + 8 * m) = s1v;
  }
}

// ---------------- fused residual-add + LayerNorm ----------------
__global__ __launch_bounds__(256) void k_add_ln(
    const float* __restrict__ a, const float* __restrict__ bmat,
    const float* __restrict__ gam, const float* __restrict__ bet,
    float* __restrict__ outf, u16* __restrict__ outb) {
  const int row = blockIdx.x;
  const int t = threadIdx.x;
  __shared__ float red[8];
  float4 va = ((const float4*)(a + (size_t)row * EMBED))[t];
  float4 vb = ((const float4*)(bmat + (size_t)row * EMBED))[t];
  float s0 = va.x + vb.x, s1 = va.y + vb.y, s2 = va.z + vb.z, s3 = va.w + vb.w;
  float sum = s0 + s1 + s2 + s3;
  float sq = s0 * s0 + s1 * s1 + s2 * s2 + s3 * s3;
  #pragma unroll
  for (int m = 1; m < 64; m <<= 1) {
    sum += __shfl_xor(sum, m, 64);
    sq += __shfl_xor(sq, m, 64);
  }
  int wid = t >> 6;
  if ((t & 63) == 0) { red[wid] = sum; red[4 + wid] = sq; }
  __syncthreads();
  sum = red[0] + red[1] + red[2] + red[3];
  sq = red[4] + red[5] + red[6] + red[7];
  float mean = sum * (1.f / EMBED);
  float var = sq * (1.f / EMBED) - mean * mean;
  float rstd = rsqrtf(var + 1e-5f);
  float4 gv = ((const float4*)gam)[t], bev = ((const float4*)bet)[t];
  float y0 = (s0 - mean) * rstd * gv.x + bev.x;
  float y1 = (s1 - mean) * rstd * gv.y + bev.y;
  float y2 = (s2 - mean) * rstd * gv.z + bev.z;
  float y3 = (s3 - mean) * rstd * gv.w + bev.w;
  if (outf) {
    float4 o; o.x = y0; o.y = y1; o.z = y2; o.w = y3;
    ((float4*)(outf + (size_t)row * EMBED))[t] = o;
  }
  if (outb) {
    ushort4 ob; ob.x = f2bf(y0); ob.y = f2bf(y1); ob.z = f2bf(y2); ob.w = f2bf(y3);
    ((ushort4*)(outb + (size_t)row * EMBED))[t] = ob;
  }
}

// ------- fused 4-partial split-K combine + residual + bias + LayerNorm -------
__global__ __launch_bounds__(256) void k_add_ln4(
    const float* __restrict__ a, const float* __restrict__ parts,
    const float* __restrict__ bias,
    const float* __restrict__ gam, const float* __restrict__ bet,
    float* __restrict__ outf) {
  const int row = blockIdx.x;
  const int t = threadIdx.x;
  __shared__ float red[8];
  float4 va = ((const float4*)(a + (size_t)row * EMBED))[t];
  float4 bv = ((const float4*)bias)[t];
  float s0 = va.x + bv.x, s1 = va.y + bv.y, s2 = va.z + bv.z, s3 = va.w + bv.w;
  #pragma unroll
  for (int c = 0; c < 4; ++c) {
    float4 pv = ((const float4*)(parts + (size_t)c * MTOT * EMBED + (size_t)row * EMBED))[t];
    s0 += pv.x; s1 += pv.y; s2 += pv.z; s3 += pv.w;
  }
  float sum = s0 + s1 + s2 + s3;
  float sq = s0 * s0 + s1 * s1 + s2 * s2 + s3 * s3;
  #pragma unroll
  for (int m = 1; m < 64; m <<= 1) {
    sum += __shfl_xor(sum, m, 64);
    sq += __shfl_xor(sq, m, 64);
  }
  int wid = t >> 6;
  if ((t & 63) == 0) { red[wid] = sum; red[4 + wid] = sq; }
  __syncthreads();
  sum = red[0] + red[1] + red[2] + red[3];
  sq = red[4] + red[5] + red[6] + red[7];
  float mean = sum * (1.f / EMBED);
  float var = sq * (1.f / EMBED) - mean * mean;
  float rstd = rsqrtf(var + 1e-5f);
  float4 gv = ((const float4*)gam)[t], bev = ((const float4*)bet)[t];
  float4 o;
  o.x = (s0 - mean) * rstd * gv.x + bev.x;
  o.y = (s1 - mean) * rstd * gv.y + bev.y;
  o.z = (s2 - mean) * rstd * gv.z + bev.z;
  o.w = (s3 - mean) * rstd * gv.w + bev.w;
  ((float4*)(outf + (size_t)row * EMBED))[t] = o;
}

extern "C" void kernel_launch(void* const* d_in, const int* in_sizes, int n_in,
                              void* d_out, int out_size, void* d_ws, size_t ws_size,
                              hipStream_t stream) {
  const float* x      = (const float*)d_in[0];
  const float* w_qkv  = (const float*)d_in[1];
  const float* b_qkv  = (const float*)d_in[2];
  const float* w_out  = (const float*)d_in[3];
  const float* b_out  = (const float*)d_in[4];
  const float* w_up   = (const float*)d_in[5];
  const float* b_up   = (const float*)d_in[6];
  const float* w_down = (const float*)d_in[7];
  const float* b_down = (const float*)d_in[8];
  const float* g1  = (const float*)d_in[9];
  const float* be1 = (const float*)d_in[10];
  const float* g2  = (const float*)d_in[11];
  const float* be2 = (const float*)d_in[12];

  char* ws = (char*)d_ws;
  size_t off = 0;
  auto alloc = [&](size_t bytes) { void* p = ws + off; off += (bytes + 255) & ~(size_t)255; return p; };

  u16* xb     = (u16*)alloc((size_t)MTOT * EMBED * 2);
  u16* wqkvT  = (u16*)alloc((size_t)3 * EMBED * EMBED * 2);
  u16* woutT  = (u16*)alloc((size_t)EMBED * EMBED * 2);
  u16* wupT   = (u16*)alloc((size_t)FFN * EMBED * 2);
  u16* wdownT = (u16*)alloc((size_t)EMBED * FFN * 2);
  u16* qp     = (u16*)alloc((size_t)MTOT * EMBED * 2);   // fragment-packed Q
  u16* kp     = (u16*)alloc((size_t)MTOT * EMBED * 2);   // fragment-packed K
  u16* vp     = (u16*)alloc((size_t)MTOT * EMBED * 2);   // fragment-packed V
  u16* ctx    = (u16*)alloc((size_t)MTOT * EMBED * 2);
  float* attn_proj = (float*)alloc((size_t)MTOT * EMBED * 4);
  float* y_f32     = (float*)alloc((size_t)MTOT * EMBED * 4);
  u16* y_bf16      = (u16*)alloc((size_t)MTOT * EMBED * 2);
  u16* hmid        = (u16*)alloc((size_t)MTOT * FFN * 2);
  float* fparts    = (float*)alloc((size_t)4 * MTOT * EMBED * 4);  // down-proj split-K partials

  dim3 trb(32, 8);
  k_cvt<<<2048, 256, 0, stream>>>(x, xb, MTOT * EMBED / 4);
  k_tr<<<dim3(3 * EMBED / 32, EMBED / 32), trb, 0, stream>>>(w_qkv, wqkvT, EMBED, 3 * EMBED);
  k_tr<<<dim3(EMBED / 32, EMBED / 32), trb, 0, stream>>>(w_out, woutT, EMBED, EMBED);
  k_tr<<<dim3(FFN / 32, EMBED / 32), trb, 0, stream>>>(w_up, wupT, EMBED, FFN);
  k_tr<<<dim3(EMBED / 32, FFN / 32), trb, 0, stream>>>(w_down, wdownT, FFN, EMBED);

  k_gemm8<2, false><<<dim3(3 * EMBED / 256, MTOT / 256), 512, 0, stream>>>(
      xb, wqkvT, b_qkv, qp, kp, vp, MTOT, 3 * EMBED, EMBED, EMBED);

  k_attn7<<<dim3(BATCH * HEADS, 64), 256, 0, stream>>>(qp, kp, vp, ctx);

  k_gemmD<false><<<dim3(EMBED / 128, MTOT / 128), 512, 0, stream>>>(
      ctx, woutT, b_out, attn_proj, MTOT, EMBED, EMBED);

  k_add_ln<<<MTOT, 256, 0, stream>>>(x, attn_proj, g1, be1, y_f32, y_bf16);

  k_gemm8<0, true><<<dim3(FFN / 256, MTOT / 256), 512, 0, stream>>>(
      y_bf16, wupT, b_up, hmid, nullptr, nullptr, MTOT, FFN, EMBED, EMBED);

  k_gemm8<3, false><<<dim3(EMBED / 256, MTOT / 256, 4), 512, 0, stream>>>(
      hmid, wdownT, nullptr, fparts, nullptr, nullptr, MTOT, EMBED, FFN / 4, FFN);

  k_add_ln4<<<MTOT, 256, 0, stream>>>(y_f32, fparts, b_down, g2, be2, (float*)d_out);

  (void)in_sizes; (void)n_in; (void)out_size; (void)ws_size;
}